// Round 2
// baseline (852.331 us; speedup 1.0000x reference)
//
#include <hip/hip_runtime.h>
#include <math.h>

// ---------------- problem constants ----------------
#define T_TOK 4096   // tokens (2*2048)
#define NE    8      // experts
#define DM    1024   // d_model
#define FF    4096   // d_ff
#define MAXS  9216   // max padded slots: 8192 pairs + 8*127 padding, rounded up
#define MAX_TILES 72 // max sum of ceil(cnt_e/128) = 64 + 7 (+1 slack)
#define BM 128
#define BN 128
#define BK 64

using bf16x8 = __attribute__((ext_vector_type(8))) __bf16;
using f32x4  = __attribute__((ext_vector_type(4))) float;

// ---------------- helpers ----------------
__device__ __forceinline__ float bf2f(unsigned short u) {
    union { float f; unsigned int i; } v; v.i = ((unsigned int)u) << 16; return v.f;
}
__device__ __forceinline__ unsigned short f2bf(float f) {
    union { float f; unsigned int u; } v; v.f = f;
    unsigned int u = v.u;
    unsigned int r = (u + 0x7fffu + ((u >> 16) & 1u)) >> 16;   // RNE
    return (unsigned short)r;
}
__device__ __forceinline__ void load_bf4(const unsigned short* p, float* f) {
    uint2 u = *(const uint2*)p;
    f[0] = bf2f((unsigned short)(u.x & 0xffffu));
    f[1] = bf2f((unsigned short)(u.x >> 16));
    f[2] = bf2f((unsigned short)(u.y & 0xffffu));
    f[3] = bf2f((unsigned short)(u.y >> 16));
}
// async global->LDS, 16B per lane. LDS dest must be wave-uniform-base + lane*16.
__device__ __forceinline__ void gl2lds16(unsigned short* lds, const unsigned short* g) {
    __builtin_amdgcn_global_load_lds((__attribute__((address_space(1))) void*)g,
                                     (__attribute__((address_space(3))) void*)lds,
                                     16, 0, 0);
}

// ---------------- K0: zero expert counters ----------------
__global__ void k_init(int* counts) {
    if (threadIdx.x < NE) counts[threadIdx.x] = 0;
}

// ---------------- Kc: fp32 -> bf16 weight conversion ----------------
__global__ __launch_bounds__(256) void k_cvt(const float* __restrict__ src,
                                             unsigned short* __restrict__ dst, int n4) {
    int i = blockIdx.x * 256 + threadIdx.x;
    if (i >= n4) return;
    float4 v = ((const float4*)src)[i];
    unsigned int o01 = f2bf(v.x) | ((unsigned int)f2bf(v.y) << 16);
    unsigned int o23 = f2bf(v.z) | ((unsigned int)f2bf(v.w) << 16);
    uint2 st; st.x = o01; st.y = o23;
    ((uint2*)dst)[i] = st;
}

// ---------------- K1: gating + rms, all fp32 (one wave per token) ----------------
__global__ __launch_bounds__(256) void k_gate(
    const float* __restrict__ x, const float* __restrict__ gw,
    float* __restrict__ invr, int* __restrict__ tok_e, float* __restrict__ tok_w,
    int* __restrict__ counts)
{
    int gid  = blockIdx.x * 256 + threadIdx.x;
    int t    = gid >> 6;
    int lane = gid & 63;
    const float* xr = x + (size_t)t * DM;
    float ss = 0.f;
    float g[NE];
#pragma unroll
    for (int e = 0; e < NE; ++e) g[e] = 0.f;
#pragma unroll
    for (int c = 0; c < 4; ++c) {
        int d = c * 256 + lane * 4;
        float4 xv = *(const float4*)(xr + d);
        ss += xv.x*xv.x + xv.y*xv.y + xv.z*xv.z + xv.w*xv.w;
#pragma unroll
        for (int e = 0; e < NE; ++e) {
            float4 wv = *(const float4*)(gw + (size_t)e * DM + d);
            g[e] += xv.x*wv.x + xv.y*wv.y + xv.z*wv.z + xv.w*wv.w;
        }
    }
#pragma unroll
    for (int off = 32; off > 0; off >>= 1) {
        ss += __shfl_down(ss, off);
#pragma unroll
        for (int e = 0; e < NE; ++e) g[e] += __shfl_down(g[e], off);
    }
    if (lane == 0) {
        invr[t] = rsqrtf(ss * (1.f / DM) + 1e-6f);
        float s0 = g[0]; int e0 = 0;
#pragma unroll
        for (int e = 1; e < NE; ++e) if (g[e] > s0) { s0 = g[e]; e0 = e; }
        float s1 = -1e30f; int e1 = 0;
#pragma unroll
        for (int e = 0; e < NE; ++e) if (e != e0 && g[e] > s1) { s1 = g[e]; e1 = e; }
        float ex = __expf(s1 - s0);           // s1 <= s0, safe
        float den = 1.f / (1.f + ex);
        tok_e[t*2]   = e0;  tok_e[t*2+1] = e1;
        tok_w[t*2]   = den; tok_w[t*2+1] = ex * den;
        atomicAdd(&counts[e0], 1);
        atomicAdd(&counts[e1], 1);
    }
}

// ---------------- K2: segment scan + tile table + pair-array init ----------------
__global__ void k_scan(const int* __restrict__ counts, int* __restrict__ cursor,
                       int* __restrict__ ntp, int* __restrict__ tile_e, int* __restrict__ tile_m0,
                       int* __restrict__ pair_tok, float* __restrict__ pair_w, int* __restrict__ pair_e)
{
    __shared__ int sseg[NE + 1];
    if (threadIdx.x == 0) {
        int acc = 0, nt = 0;
        for (int e = 0; e < NE; ++e) {
            sseg[e] = acc;
            cursor[e] = acc;
            int ct = counts[e];
            int tiles = (ct + BM - 1) / BM;
            for (int t2 = 0; t2 < tiles; ++t2) { tile_e[nt] = e; tile_m0[nt] = acc + t2 * BM; ++nt; }
            acc += tiles * BM;     // 128-padded segments
        }
        sseg[NE] = acc;
        ntp[0] = nt;
        for (int t2 = nt; t2 < MAX_TILES; ++t2) { tile_e[t2] = 0; tile_m0[t2] = 0; }
    }
    __syncthreads();
    for (int i = threadIdx.x; i < MAXS; i += blockDim.x) {
        pair_tok[i] = 0;      // padding rows alias token 0 (finite data, weight 0)
        pair_w[i]   = 0.f;
        int e = NE - 1;
        for (int j = 0; j < NE; ++j) if (i < sseg[j + 1]) { e = j; break; }
        pair_e[i] = e;
    }
}

// ---------------- K3: scatter tokens to expert-grouped slots ----------------
__global__ __launch_bounds__(256) void k_scatter(
    const int* __restrict__ tok_e, const float* __restrict__ tok_w, int* __restrict__ cursor,
    int* __restrict__ pair_tok, float* __restrict__ pair_w, int* __restrict__ tok_slot)
{
    int t = blockIdx.x * 256 + threadIdx.x;
    if (t >= T_TOK) return;
#pragma unroll
    for (int k = 0; k < 2; ++k) {
        int e = tok_e[t*2 + k];
        int pos = atomicAdd(&cursor[e], 1);
        pair_tok[pos] = t;
        pair_w[pos]   = tok_w[t*2 + k];
        tok_slot[t*2 + k] = pos;
    }
}

// ---------------- K4: build gathered+normalized A (bf16), ln_w folded in ----------------
__global__ __launch_bounds__(256) void k_build_ag(
    const float* __restrict__ x, const float* __restrict__ lnw,
    const float* __restrict__ invr, const int* __restrict__ pair_tok, const int* __restrict__ pair_e,
    unsigned short* __restrict__ Ag)
{
    int slot = blockIdx.x * 4 + (threadIdx.x >> 6);
    int lane = threadIdx.x & 63;
    int tok = pair_tok[slot];
    int e   = pair_e[slot];
    float sc = invr[tok];
    const float* xr = x + (size_t)tok * DM;
    const float* lr = lnw + (size_t)e * DM;
    unsigned short* orow = Ag + (size_t)slot * DM;
#pragma unroll
    for (int c = 0; c < 4; ++c) {
        int d = c * 256 + lane * 4;
        float4 xv = *(const float4*)(xr + d);
        float4 lv = *(const float4*)(lr + d);
        unsigned int o01 = f2bf(xv.x*sc*lv.x) | ((unsigned int)f2bf(xv.y*sc*lv.y) << 16);
        unsigned int o23 = f2bf(xv.z*sc*lv.z) | ((unsigned int)f2bf(xv.w*sc*lv.w) << 16);
        uint2 st; st.x = o01; st.y = o23;
        *(uint2*)(orow + d) = st;
    }
}

// ---------------- K5: grouped GEMM1: h = silu(A w1^T) * (A w3^T) ----------------
// 128x128 tile, BK=64, 16x16x32 bf16 MFMA, XOR-swizzled LDS, global_load_lds staging.
__global__ __launch_bounds__(256, 2) void k_gemm1(
    const unsigned short* __restrict__ Ag, const unsigned short* __restrict__ w1,
    const unsigned short* __restrict__ w3, unsigned short* __restrict__ Hb,
    const int* __restrict__ ntp, const int* __restrict__ tile_e, const int* __restrict__ tile_m0)
{
    int tile = blockIdx.x;
    if (tile >= ntp[0]) return;
    int e  = tile_e[tile];
    int m0 = tile_m0[tile];
    int n0 = blockIdx.y * BN;

    __shared__ __align__(16) unsigned short As[BM * BK];
    __shared__ __align__(16) unsigned short B1s[BN * BK];
    __shared__ __align__(16) unsigned short B3s[BN * BK];

    int tid = threadIdx.x;
    int lane = tid & 63, wv = tid >> 6;
    int wm = wv >> 1, wn = wv & 1;           // 2x2 wave grid, 64x64 per wave

    const unsigned short* Abase  = Ag + (size_t)m0 * DM;
    const unsigned short* B1base = w1 + (size_t)e * FF * DM + (size_t)n0 * DM;
    const unsigned short* B3base = w3 + (size_t)e * FF * DM + (size_t)n0 * DM;

    f32x4 acc1[4][4], acc3[4][4];
#pragma unroll
    for (int i = 0; i < 4; ++i)
#pragma unroll
        for (int j = 0; j < 4; ++j) { acc1[i][j] = (f32x4)(0.f); acc3[i][j] = (f32x4)(0.f); }

    int q  = lane >> 4;        // quad
    int rr = lane & 15;

    for (int kk = 0; kk < DM; kk += BK) {
        // stage: LDS granule gi holds global granule (gi&7)^(row&7) of row gi>>3
#pragma unroll
        for (int p = 0; p < 4; ++p) {
            int gi = p * 256 + tid;
            int r = gi >> 3, s = gi & 7;
            int sg = s ^ (r & 7);
            size_t src = (size_t)r * DM + kk + sg * 8;
            gl2lds16(&As[gi * 8],  Abase  + src);
            gl2lds16(&B1s[gi * 8], B1base + src);
            gl2lds16(&B3s[gi * 8], B3base + src);
        }
        __syncthreads();       // drains vmcnt -> LDS valid
#pragma unroll
        for (int ks = 0; ks < 2; ++ks) {
            int g = ks * 4 + q;                 // k-granule for this quad
            bf16x8 af[4], b1f[4], b3f[4];
#pragma unroll
            for (int i = 0; i < 4; ++i) {
                int row = wm * 64 + i * 16 + rr;
                af[i] = *(const bf16x8*)&As[row * 64 + ((g ^ (row & 7)) << 3)];
            }
#pragma unroll
            for (int j = 0; j < 4; ++j) {
                int row = wn * 64 + j * 16 + rr;
                int off = row * 64 + ((g ^ (row & 7)) << 3);
                b1f[j] = *(const bf16x8*)&B1s[off];
                b3f[j] = *(const bf16x8*)&B3s[off];
            }
#pragma unroll
            for (int i = 0; i < 4; ++i)
#pragma unroll
                for (int j = 0; j < 4; ++j) {
                    acc1[i][j] = __builtin_amdgcn_mfma_f32_16x16x32_bf16(af[i], b1f[j], acc1[i][j], 0, 0, 0);
                    acc3[i][j] = __builtin_amdgcn_mfma_f32_16x16x32_bf16(af[i], b3f[j], acc3[i][j], 0, 0, 0);
                }
        }
        __syncthreads();       // protect LDS before restage
    }

    // epilogue: fused silu(c1)*c3, bf16 store. C/D: row=(lane>>4)*4+r, col=lane&15
#pragma unroll
    for (int i = 0; i < 4; ++i) {
        int mb = wm * 64 + i * 16 + q * 4;
#pragma unroll
        for (int j = 0; j < 4; ++j) {
            int nc = n0 + wn * 64 + j * 16 + rr;
#pragma unroll
            for (int r = 0; r < 4; ++r) {
                float v1 = acc1[i][j][r];
                float v3 = acc3[i][j][r];
                float hv = (v1 / (1.f + __expf(-v1))) * v3;
                Hb[(size_t)(m0 + mb + r) * FF + nc] = f2bf(hv);
            }
        }
    }
}

// ---------------- K6: grouped GEMM2: pairout = (h w2^T) * routing_weight (bf16 out) ----------------
__global__ __launch_bounds__(256, 2) void k_gemm2(
    const unsigned short* __restrict__ Hb, const unsigned short* __restrict__ w2,
    unsigned short* __restrict__ Pout, const float* __restrict__ pair_w,
    const int* __restrict__ ntp, const int* __restrict__ tile_e, const int* __restrict__ tile_m0)
{
    int tile = blockIdx.x;
    if (tile >= ntp[0]) return;
    int e  = tile_e[tile];
    int m0 = tile_m0[tile];
    int n0 = blockIdx.y * BN;

    __shared__ __align__(16) unsigned short As[BM * BK];
    __shared__ __align__(16) unsigned short Bs[BN * BK];

    int tid = threadIdx.x;
    int lane = tid & 63, wv = tid >> 6;
    int wm = wv >> 1, wn = wv & 1;

    const unsigned short* Abase = Hb + (size_t)m0 * FF;
    const unsigned short* Bbase = w2 + (size_t)e * DM * FF + (size_t)n0 * FF;

    f32x4 acc[4][4];
#pragma unroll
    for (int i = 0; i < 4; ++i)
#pragma unroll
        for (int j = 0; j < 4; ++j) acc[i][j] = (f32x4)(0.f);

    int q = lane >> 4, rr = lane & 15;

    for (int kk = 0; kk < FF; kk += BK) {
#pragma unroll
        for (int p = 0; p < 4; ++p) {
            int gi = p * 256 + tid;
            int r = gi >> 3, s = gi & 7;
            int sg = s ^ (r & 7);
            size_t src = (size_t)r * FF + kk + sg * 8;
            gl2lds16(&As[gi * 8], Abase + src);
            gl2lds16(&Bs[gi * 8], Bbase + src);
        }
        __syncthreads();
#pragma unroll
        for (int ks = 0; ks < 2; ++ks) {
            int g = ks * 4 + q;
            bf16x8 af[4], bf[4];
#pragma unroll
            for (int i = 0; i < 4; ++i) {
                int row = wm * 64 + i * 16 + rr;
                af[i] = *(const bf16x8*)&As[row * 64 + ((g ^ (row & 7)) << 3)];
            }
#pragma unroll
            for (int j = 0; j < 4; ++j) {
                int row = wn * 64 + j * 16 + rr;
                bf[j] = *(const bf16x8*)&Bs[row * 64 + ((g ^ (row & 7)) << 3)];
            }
#pragma unroll
            for (int i = 0; i < 4; ++i)
#pragma unroll
                for (int j = 0; j < 4; ++j)
                    acc[i][j] = __builtin_amdgcn_mfma_f32_16x16x32_bf16(af[i], bf[j], acc[i][j], 0, 0, 0);
        }
        __syncthreads();
    }

#pragma unroll
    for (int i = 0; i < 4; ++i) {
        int mb = wm * 64 + i * 16 + q * 4;
#pragma unroll
        for (int j = 0; j < 4; ++j) {
            int nc = n0 + wn * 64 + j * 16 + rr;
#pragma unroll
            for (int r = 0; r < 4; ++r) {
                float pw = pair_w[m0 + mb + r];      // 0 for padding rows
                Pout[(size_t)(m0 + mb + r) * DM + nc] = f2bf(acc[i][j][r] * pw);
            }
        }
    }
}

// ---------------- K7: combine: out = x + p[slot0] + p[slot1] (fp32 out) ----------------
__global__ __launch_bounds__(256) void k_combine(
    const float* __restrict__ x, const unsigned short* __restrict__ Pout,
    const int* __restrict__ tok_slot, float* __restrict__ out)
{
    int idx = blockIdx.x * 256 + threadIdx.x;
    int t = idx >> 8;
    int d = (idx & 255) << 2;
    int s0 = tok_slot[t*2], s1 = tok_slot[t*2+1];
    float4 xv = *(const float4*)(x + (size_t)t * DM + d);
    float p0[4], p1[4];
    load_bf4(Pout + (size_t)s0 * DM + d, p0);
    load_bf4(Pout + (size_t)s1 * DM + d, p1);
    float4 o;
    o.x = xv.x + p0[0] + p1[0];
    o.y = xv.y + p0[1] + p1[1];
    o.z = xv.z + p0[2] + p1[2];
    o.w = xv.w + p0[3] + p1[3];
    *(float4*)(out + (size_t)t * DM + d) = o;
}

// ---------------- host launch ----------------
extern "C" void kernel_launch(void* const* d_in, const int* in_sizes, int n_in,
                              void* d_out, int out_size, void* d_ws, size_t ws_size,
                              hipStream_t stream)
{
    const float* x   = (const float*)d_in[0];
    const float* gw  = (const float*)d_in[1];
    const float* lnw = (const float*)d_in[2];
    const float* w1  = (const float*)d_in[3];
    const float* w3  = (const float*)d_in[4];
    const float* w2  = (const float*)d_in[5];
    float* out = (float*)d_out;

    char* p = (char*)d_ws;
    auto carve = [&](size_t bytes) { char* r = p; p += (bytes + 255) & ~(size_t)255; return r; };
    const size_t WE = (size_t)NE * FF * DM;                                  // 33.55M elems
    unsigned short* W1b  = (unsigned short*)carve(WE * 2);                   // 67.1 MB
    unsigned short* W3b  = (unsigned short*)carve(WE * 2);                   // 67.1 MB
    unsigned short* W2b  = (unsigned short*)carve(WE * 2);                   // 67.1 MB
    unsigned short* Ag   = (unsigned short*)carve((size_t)MAXS * DM * 2);    // 18.9 MB
    unsigned short* Hb   = (unsigned short*)carve((size_t)MAXS * FF * 2);    // 75.5 MB
    unsigned short* Pout = (unsigned short*)carve((size_t)MAXS * DM * 2);    // 18.9 MB
    float* invr     = (float*)carve((size_t)T_TOK * 4);
    int*   tok_e    = (int*)carve((size_t)T_TOK * 2 * 4);
    float* tok_w    = (float*)carve((size_t)T_TOK * 2 * 4);
    int*   tok_slot = (int*)carve((size_t)T_TOK * 2 * 4);
    int*   pair_tok = (int*)carve((size_t)MAXS * 4);
    float* pair_w   = (float*)carve((size_t)MAXS * 4);
    int*   pair_e   = (int*)carve((size_t)MAXS * 4);
    int*   counts   = (int*)carve(NE * 4);
    int*   cursor   = (int*)carve(NE * 4);
    int*   ntp      = (int*)carve(4);
    int*   tile_e   = (int*)carve(MAX_TILES * 4);
    int*   tile_m0  = (int*)carve(MAX_TILES * 4);

    int n4 = (int)(WE / 4);
    k_init<<<1, 64, 0, stream>>>(counts);
    k_cvt<<<(n4 + 255) / 256, 256, 0, stream>>>(w1, W1b, n4);
    k_cvt<<<(n4 + 255) / 256, 256, 0, stream>>>(w3, W3b, n4);
    k_cvt<<<(n4 + 255) / 256, 256, 0, stream>>>(w2, W2b, n4);
    k_gate<<<T_TOK * 64 / 256, 256, 0, stream>>>(x, gw, invr, tok_e, tok_w, counts);
    k_scan<<<1, 256, 0, stream>>>(counts, cursor, ntp, tile_e, tile_m0, pair_tok, pair_w, pair_e);
    k_scatter<<<(T_TOK + 255) / 256, 256, 0, stream>>>(tok_e, tok_w, cursor, pair_tok, pair_w, tok_slot);
    k_build_ag<<<MAXS / 4, 256, 0, stream>>>(x, lnw, invr, pair_tok, pair_e, Ag);
    k_gemm1<<<dim3(MAX_TILES, FF / BN), 256, 0, stream>>>(Ag, W1b, W3b, Hb, ntp, tile_e, tile_m0);
    k_gemm2<<<dim3(MAX_TILES, DM / BN), 256, 0, stream>>>(Hb, W2b, Pout, pair_w, ntp, tile_e, tile_m0);
    k_combine<<<T_TOK * DM / 4 / 256, 256, 0, stream>>>(x, Pout, tok_slot, out);
}